// Round 1
// baseline (18.540 us; speedup 1.0000x reference)
//
#include <hip/hip_runtime.h>
#include <math.h>

// HQNN: x in [0,16) -> circuit output depends only on the 4-bit value.
// Build a 16x4 LUT in LDS per block (cheap, parallel), then gather.

__global__ __launch_bounds__(256) void hqnn_kernel(
    const int* __restrict__ x,
    const float* __restrict__ weights,   // [4,4,3] flat
    const float* __restrict__ fc_w,      // [4,4] row-major
    const float* __restrict__ fc_b,      // [4]
    float* __restrict__ out,             // [B,4]
    int B)
{
    __shared__ float rot[16][8];                   // 16 Rot gates: ar ai br bi cr ci dr di
    __shared__ __align__(16) float table[16][4];   // final LUT

    const int tid = threadIdx.x;

    // ---- Phase 1: 16 Rot matrices (gate g = l*4+w), 3 sincosf each ----
    if (tid < 16) {
        const float phi   = weights[tid * 3 + 0];
        const float theta = weights[tid * 3 + 1];
        const float omega = weights[tid * 3 + 2];
        float st, ct; sincosf(0.5f * theta, &st, &ct);
        float sa, ca; sincosf(-0.5f * (phi + omega), &sa, &ca);
        float sb, cb; sincosf( 0.5f * (phi - omega), &sb, &cb);
        // a = e^{-i(phi+omega)/2} ct ; b = -e^{+i(phi-omega)/2} st
        // c = e^{-i(phi-omega)/2} st ; d = e^{+i(phi+omega)/2} ct
        rot[tid][0] =  ca * ct;   // ar
        rot[tid][1] =  sa * ct;   // ai
        rot[tid][2] = -cb * st;   // br
        rot[tid][3] = -sb * st;   // bi
        rot[tid][4] =  cb * st;   // cr
        rot[tid][5] = -sb * st;   // ci
        rot[tid][6] =  ca * ct;   // dr
        rot[tid][7] = -sa * ct;   // di
    }
    __syncthreads();

    // ---- Phase 2: simulate all 16 input values; 1 amplitude per thread ----
    // thread t: value v = t>>4, basis index amp = t&15 (wire w <-> bit (3-w))
    const int v   = tid >> 4;
    const int amp = tid & 15;

    float sr = (amp == 0) ? 1.0f : 0.0f;
    float si = 0.0f;

    // Encoding: per wire, RX(pi*b) then RZ(pi*b); b==0 -> identity
    #pragma unroll
    for (int w = 0; w < 4; ++w) {
        const int mask = 1 << (3 - w);
        const int b = (v >> (3 - w)) & 1;
        const float pr  = __shfl_xor(sr, mask);
        const float pii = __shfl_xor(si, mask);
        if (b) {
            // RX(pi): s_new = -i * partner  => (pii, -pr)
            const float nr = pii, ni = -pr;
            // RZ(pi): bit0 lane *= -i ; bit1 lane *= +i
            if (amp & mask) { sr = -ni; si =  nr; }
            else            { sr =  ni; si = -nr; }
        }
    }

    // Variational layers: CNOT ring + per-wire Rot
    #pragma unroll
    for (int l = 0; l < 4; ++l) {
        #pragma unroll
        for (int k = 0; k < 4; ++k) {
            const int c = k, t = (k + 1) & 3;
            const int mc = 1 << (3 - c), mt = 1 << (3 - t);
            const float pr  = __shfl_xor(sr, mt);
            const float pii = __shfl_xor(si, mt);
            if (amp & mc) { sr = pr; si = pii; }
        }
        #pragma unroll
        for (int w = 0; w < 4; ++w) {
            const int g = l * 4 + w;
            const int mask = 1 << (3 - w);
            const float ar = rot[g][0], ai = rot[g][1];
            const float br = rot[g][2], bi = rot[g][3];
            const float cr = rot[g][4], ci = rot[g][5];
            const float dr = rot[g][6], di = rot[g][7];
            const float pr  = __shfl_xor(sr, mask);
            const float pii = __shfl_xor(si, mask);
            float nr, ni;
            if (amp & mask) {
                // lower element of the pair: new1 = c*partner + d*self
                nr = cr * pr - ci * pii + dr * sr - di * si;
                ni = cr * pii + ci * pr + dr * si + di * sr;
            } else {
                // upper element: new0 = a*self + b*partner
                nr = ar * sr - ai * si + br * pr - bi * pii;
                ni = ar * si + ai * sr + br * pii + bi * pr;
            }
            sr = nr; si = ni;
        }
    }

    // <Z_w> per value via signed xor-butterfly over the 16-lane group
    const float prob = sr * sr + si * si;
    float ev[4];
    #pragma unroll
    for (int w = 0; w < 4; ++w) {
        float t = (amp & (1 << (3 - w))) ? -prob : prob;
        #pragma unroll
        for (int m = 1; m < 16; m <<= 1) t += __shfl_xor(t, m);
        ev[w] = t;
    }

    // Linear(4,4) + leaky_relu -> LUT
    if (amp < 4) {
        float acc = fc_b[amp];
        #pragma unroll
        for (int w = 0; w < 4; ++w) acc += ev[w] * fc_w[amp * 4 + w];
        table[v][amp] = (acc >= 0.0f) ? acc : 0.01f * acc;
    }
    __syncthreads();

    // ---- Phase 3: gather (memory-bound part) ----
    const int gid = blockIdx.x * 256 + tid;
    const int stride = gridDim.x * 256;
    float4* __restrict__ out4 = reinterpret_cast<float4*>(out);
    const float4* tab4 = reinterpret_cast<const float4*>(&table[0][0]);
    for (int b = gid; b < B; b += stride) {
        const int vv = x[b] & 15;
        out4[b] = tab4[vv];
    }
}

extern "C" void kernel_launch(void* const* d_in, const int* in_sizes, int n_in,
                              void* d_out, int out_size, void* d_ws, size_t ws_size,
                              hipStream_t stream) {
    const int*   x       = (const int*)d_in[0];
    const float* weights = (const float*)d_in[1];
    const float* fc_w    = (const float*)d_in[2];
    const float* fc_b    = (const float*)d_in[3];
    float*       out     = (float*)d_out;
    const int B = in_sizes[0];
    int blocks = (B + 255) / 256;
    if (blocks > 2048) blocks = 2048;
    hqnn_kernel<<<blocks, 256, 0, stream>>>(x, weights, fc_w, fc_b, out, B);
}

// Round 3
// 17.100 us; speedup vs baseline: 1.0842x; 1.0842x over previous
//
#include <hip/hip_runtime.h>
#include <math.h>

// HQNN: x in [0,16) -> circuit output depends only on the 4-bit value.
// Build a 16x4 LUT in LDS per block (cheap, parallel), then gather.
// R1: __sinf/__cosf instead of ocml sincosf; WHT butterfly reduction;
//     prefetch x before the sim; nontemporal streaming loads/stores.
// R2: native ext_vector float4 (HIP_vector_type rejected by nontemporal builtin).

typedef float f4 __attribute__((ext_vector_type(4)));

__global__ __launch_bounds__(256) void hqnn_kernel(
    const int* __restrict__ x,
    const float* __restrict__ weights,   // [4,4,3] flat
    const float* __restrict__ fc_w,      // [4,4] row-major
    const float* __restrict__ fc_b,      // [4]
    float* __restrict__ out,             // [B,4]
    int B)
{
    __shared__ float rot[16][8];                   // 16 Rot gates: ar ai br bi cr ci dr di
    __shared__ float evs[16][4];                   // <Z_w> per value
    __shared__ __align__(16) float table[16][4];   // final LUT

    const int tid = threadIdx.x;
    const int gid = blockIdx.x * 256 + tid;
    const int stride = gridDim.x * 256;

    // ---- Prefetch the gather indices early (independent of the sim) ----
    const int b0 = gid, b1 = gid + stride;
    const bool h0 = b0 < B, h1 = b1 < B;
    int v0 = 0, v1 = 0;
    if (h0) v0 = __builtin_nontemporal_load(&x[b0]) & 15;
    if (h1) v1 = __builtin_nontemporal_load(&x[b1]) & 15;

    // ---- Phase 1: 16 Rot matrices (gate g = l*4+w), fast HW trig ----
    if (tid < 16) {
        const float phi   = weights[tid * 3 + 0];
        const float theta = weights[tid * 3 + 1];
        const float omega = weights[tid * 3 + 2];
        const float ht = 0.5f * theta;
        const float ha = -0.5f * (phi + omega);
        const float hb =  0.5f * (phi - omega);
        const float st = __sinf(ht), ct = __cosf(ht);
        const float sa = __sinf(ha), ca = __cosf(ha);
        const float sb = __sinf(hb), cb = __cosf(hb);
        // a = e^{-i(phi+omega)/2} ct ; b = -e^{+i(phi-omega)/2} st
        // c = e^{-i(phi-omega)/2} st ; d = e^{+i(phi+omega)/2} ct
        rot[tid][0] =  ca * ct;   // ar
        rot[tid][1] =  sa * ct;   // ai
        rot[tid][2] = -cb * st;   // br
        rot[tid][3] = -sb * st;   // bi
        rot[tid][4] =  cb * st;   // cr
        rot[tid][5] = -sb * st;   // ci
        rot[tid][6] =  ca * ct;   // dr
        rot[tid][7] = -sa * ct;   // di
    }
    __syncthreads();

    // ---- Phase 2: simulate all 16 input values; 1 amplitude per thread ----
    // thread t: value v = t>>4, basis index amp = t&15 (wire w <-> bit (3-w))
    const int v   = tid >> 4;
    const int amp = tid & 15;

    float sr = (amp == 0) ? 1.0f : 0.0f;
    float si = 0.0f;

    // Encoding: per wire, RX(pi*b) then RZ(pi*b); b==0 -> identity
    #pragma unroll
    for (int w = 0; w < 4; ++w) {
        const int mask = 1 << (3 - w);
        const int b = (v >> (3 - w)) & 1;
        const float pr  = __shfl_xor(sr, mask);
        const float pii = __shfl_xor(si, mask);
        if (b) {
            // RX(pi): s_new = -i * partner  => (pii, -pr)
            const float nr = pii, ni = -pr;
            // RZ(pi): bit0 lane *= -i ; bit1 lane *= +i
            if (amp & mask) { sr = -ni; si =  nr; }
            else            { sr =  ni; si = -nr; }
        }
    }

    // Variational layers: CNOT ring + per-wire Rot
    #pragma unroll
    for (int l = 0; l < 4; ++l) {
        #pragma unroll
        for (int k = 0; k < 4; ++k) {
            const int c = k, t = (k + 1) & 3;
            const int mc = 1 << (3 - c), mt = 1 << (3 - t);
            const float pr  = __shfl_xor(sr, mt);
            const float pii = __shfl_xor(si, mt);
            if (amp & mc) { sr = pr; si = pii; }
        }
        #pragma unroll
        for (int w = 0; w < 4; ++w) {
            const int g = l * 4 + w;
            const int mask = 1 << (3 - w);
            const float ar = rot[g][0], ai = rot[g][1];
            const float br = rot[g][2], bi = rot[g][3];
            const float cr = rot[g][4], ci = rot[g][5];
            const float dr = rot[g][6], di = rot[g][7];
            const float pr  = __shfl_xor(sr, mask);
            const float pii = __shfl_xor(si, mask);
            float nr, ni;
            if (amp & mask) {
                // lower element of the pair: new1 = c*partner + d*self
                nr = cr * pr - ci * pii + dr * sr - di * si;
                ni = cr * pii + ci * pr + dr * si + di * sr;
            } else {
                // upper element: new0 = a*self + b*partner
                nr = ar * sr - ai * si + br * pr - bi * pii;
                ni = ar * si + ai * sr + br * pii + bi * pr;
            }
            sr = nr; si = ni;
        }
    }

    // Walsh-Hadamard butterfly over the 16-lane group: lane j ends with
    // H[j] = sum_a (-1)^{popcount(a&j)} p[a]; ev[w] = H[1<<(3-w)].
    float h = sr * sr + si * si;
    #pragma unroll
    for (int m = 1; m < 16; m <<= 1) {
        const float t = __shfl_xor(h, m);
        h = (amp & m) ? (t - h) : (t + h);
    }
    if (amp == 1 || amp == 2 || amp == 4 || amp == 8) {
        const int p = __ffs(amp) - 1;      // bit position
        evs[v][3 - p] = h;
    }
    __syncthreads();

    // Linear(4,4) + leaky_relu -> LUT
    if (amp < 4) {
        float acc = fc_b[amp];
        #pragma unroll
        for (int w = 0; w < 4; ++w) acc += evs[v][w] * fc_w[amp * 4 + w];
        table[v][amp] = (acc >= 0.0f) ? acc : 0.01f * acc;
    }
    __syncthreads();

    // ---- Phase 3: gather (memory-bound part) ----
    f4* __restrict__ out4 = reinterpret_cast<f4*>(out);
    const f4* tab4 = reinterpret_cast<const f4*>(&table[0][0]);
    if (h0) __builtin_nontemporal_store(tab4[v0], &out4[b0]);
    if (h1) __builtin_nontemporal_store(tab4[v1], &out4[b1]);
    for (int b = gid + 2 * stride; b < B; b += stride) {
        const int vv = x[b] & 15;
        __builtin_nontemporal_store(tab4[vv], &out4[b]);
    }
}

extern "C" void kernel_launch(void* const* d_in, const int* in_sizes, int n_in,
                              void* d_out, int out_size, void* d_ws, size_t ws_size,
                              hipStream_t stream) {
    const int*   x       = (const int*)d_in[0];
    const float* weights = (const float*)d_in[1];
    const float* fc_w    = (const float*)d_in[2];
    const float* fc_b    = (const float*)d_in[3];
    float*       out     = (float*)d_out;
    const int B = in_sizes[0];
    int blocks = (B + 255) / 256;
    if (blocks > 2048) blocks = 2048;
    hqnn_kernel<<<blocks, 256, 0, stream>>>(x, weights, fc_w, fc_b, out, B);
}

// Round 4
// 11.691 us; speedup vs baseline: 1.5859x; 1.4627x over previous
//
#include <hip/hip_runtime.h>
#include <math.h>

// HQNN: x in [0,16) -> output depends only on the 4-bit value. Build a 16x4
// LUT per block, then gather.
// R3: encoding gates eliminated analytically (RZpi*RXpi = [[0,-1],[1,0]] =>
//     state == |v>, amp +1 exactly); 4-CNOT ring fused to ONE ds_bpermute per
//     layer (precomputed composite permutation address); rot gates stored as
//     4 floats {A,B,C,D} (one ds_read_b128 each); 1024 blocks (4/CU) to halve
//     redundant per-CU preamble DS pressure; all 4 x-loads prefetched pre-sim.

typedef float f4 __attribute__((ext_vector_type(4)));

__device__ __forceinline__ float bperm(int addr, float v) {
    return __int_as_float(__builtin_amdgcn_ds_bpermute(addr, __float_as_int(v)));
}

__global__ __launch_bounds__(256) void hqnn_kernel(
    const int* __restrict__ x,
    const float* __restrict__ weights,   // [4,4,3] flat
    const float* __restrict__ fc_w,      // [4,4] row-major
    const float* __restrict__ fc_b,      // [4]
    float* __restrict__ out,             // [B,4]
    int B)
{
    __shared__ __align__(16) float rot4[16][4];    // gate g: {A,B,C,D}
    __shared__ float evs[16][4];                   // <Z_w> per value
    __shared__ __align__(16) float table[16][4];   // final LUT

    const int tid = threadIdx.x;
    const int gid = blockIdx.x * 256 + tid;
    const int stride = gridDim.x * 256;

    // ---- Prefetch all gather indices before the sim (latency hides) ----
    int  vv[4];
    bool hv[4];
    #pragma unroll
    for (int k = 0; k < 4; ++k) {
        const int b = gid + k * stride;
        hv[k] = (b < B);
        vv[k] = hv[k] ? (__builtin_nontemporal_load(&x[b]) & 15) : 0;
    }

    // ---- Phase 1: 16 Rot gates -> {A,B,C,D}; a=A+iB b=-C-iD c=C-iD d=A-iB
    if (tid < 16) {
        const float phi   = weights[tid * 3 + 0];
        const float theta = weights[tid * 3 + 1];
        const float omega = weights[tid * 3 + 2];
        const float ht = 0.5f * theta;
        const float ha = -0.5f * (phi + omega);
        const float hb =  0.5f * (phi - omega);
        const float st = __sinf(ht), ct = __cosf(ht);
        const float sa = __sinf(ha), ca = __cosf(ha);
        const float sb = __sinf(hb), cb = __cosf(hb);
        rot4[tid][0] = ca * ct;   // A
        rot4[tid][1] = sa * ct;   // B
        rot4[tid][2] = cb * st;   // C
        rot4[tid][3] = sb * st;   // D
    }

    // ---- Composite CNOT-ring read address (same every layer) ----
    // lane j reads amp f0(f1(f2(f3(j)))), fk = "flip target if control set"
    const int lane = tid & 63;
    const int amp  = tid & 15;
    const int v    = tid >> 4;
    int q = amp;
    q ^= (q & 1) << 3;          // f3: CNOT(3,0)  ctrl bit0 -> tgt bit3
    q ^= (q >> 1) & 1;          // f2: CNOT(2,3)  ctrl bit1 -> tgt bit0
    q ^= ((q >> 2) & 1) << 1;   // f1: CNOT(1,2)  ctrl bit2 -> tgt bit1
    q ^= ((q >> 3) & 1) << 2;   // f0: CNOT(0,1)  ctrl bit3 -> tgt bit2
    const int paddr = (((lane & 48) | q) << 2);

    __syncthreads();

    // ---- Phase 2: encoded state is exactly |v> ----
    float sr = (amp == v) ? 1.0f : 0.0f;
    float si = 0.0f;

    #pragma unroll
    for (int l = 0; l < 4; ++l) {
        // whole CNOT ring in one pull per component
        sr = bperm(paddr, sr);
        si = bperm(paddr, si);
        #pragma unroll
        for (int w = 0; w < 4; ++w) {
            const int g = l * 4 + w;
            const int mask = 1 << (3 - w);
            const f4 gv = *reinterpret_cast<const f4*>(&rot4[g][0]);
            const float A = gv.x, Bc = gv.y, C = gv.z, D = gv.w;
            const float pr  = __shfl_xor(sr, mask);
            const float pii = __shfl_xor(si, mask);
            float nr, ni;
            if (amp & mask) {   // lower: c*partner + d*self
                nr = C * pr + D * pii + A * sr + Bc * si;
                ni = C * pii - D * pr + A * si - Bc * sr;
            } else {            // upper: a*self + b*partner
                nr = A * sr - Bc * si - C * pr + D * pii;
                ni = A * si + Bc * sr - C * pii - D * pr;
            }
            sr = nr; si = ni;
        }
    }

    // Walsh-Hadamard over the 16-lane group: lane j -> H[j]; ev[w]=H[1<<(3-w)]
    float h = sr * sr + si * si;
    #pragma unroll
    for (int m = 1; m < 16; m <<= 1) {
        const float t = __shfl_xor(h, m);
        h = (amp & m) ? (t - h) : (t + h);
    }
    if (amp == 1 || amp == 2 || amp == 4 || amp == 8) {
        const int p = __ffs(amp) - 1;
        evs[v][3 - p] = h;
    }
    __syncthreads();

    // Linear(4,4) + leaky_relu -> LUT
    if (amp < 4) {
        float acc = fc_b[amp];
        #pragma unroll
        for (int w = 0; w < 4; ++w) acc += evs[v][w] * fc_w[amp * 4 + w];
        table[v][amp] = (acc >= 0.0f) ? acc : 0.01f * acc;
    }
    __syncthreads();

    // ---- Phase 3: streaming gather ----
    f4* __restrict__ out4 = reinterpret_cast<f4*>(out);
    const f4* tab4 = reinterpret_cast<const f4*>(&table[0][0]);
    #pragma unroll
    for (int k = 0; k < 4; ++k) {
        if (hv[k]) __builtin_nontemporal_store(tab4[vv[k]], &out4[gid + k * stride]);
    }
    for (int b = gid + 4 * stride; b < B; b += stride) {   // generic tail
        const int vvt = x[b] & 15;
        __builtin_nontemporal_store(tab4[vvt], &out4[b]);
    }
}

extern "C" void kernel_launch(void* const* d_in, const int* in_sizes, int n_in,
                              void* d_out, int out_size, void* d_ws, size_t ws_size,
                              hipStream_t stream) {
    const int*   x       = (const int*)d_in[0];
    const float* weights = (const float*)d_in[1];
    const float* fc_w    = (const float*)d_in[2];
    const float* fc_b    = (const float*)d_in[3];
    float*       out     = (float*)d_out;
    const int B = in_sizes[0];
    int blocks = (B + 255) / 256;
    if (blocks > 1024) blocks = 1024;
    hqnn_kernel<<<blocks, 256, 0, stream>>>(x, weights, fc_w, fc_b, out, B);
}